// Round 3
// baseline (498.826 us; speedup 1.0000x reference)
//
#include <hip/hip_runtime.h>
#include <math.h>

// Sudoku iterative solver: one workgroup per batch row, whole 81-step scan
// runs inside the kernel (rows are independent -> no grid sync needed).
// State (x, x_pred, group sums, hidden acts) lives in LDS; W1 rows live in
// registers (thread t<200 owns hidden unit u=t%100).
//
// Numerics: strictly sequential fp32 FMA accumulation (k ascending) for both
// GEMM layers, jax.nn.softmax semantics (sub max, expf, true division),
// first-index tie-break on both argmaxes (cell-index ordered, independent of
// the atomic compaction order) -- to track the reference argmax trajectory.

#define NCELL 81
#define ND 9
#define NH 100
#define NTHREADS 256
#define CHUNK 64

// Layer-1 for one cell: 27 sequential FMAs in reference k-order
// (row sums, col sums, box sums).
__device__ __forceinline__ float l1_cell(const float* __restrict__ gsum,
                                         const float* __restrict__ w1r,
                                         int cell)
{
    int r  = cell / 9, cc = cell % 9;
    int bx = (r / 3) * 3 + cc / 3;
    const float* fr = &gsum[r * ND];            // broadcast LDS reads
    const float* fc = &gsum[(9 + cc) * ND];
    const float* fb = &gsum[(18 + bx) * ND];
    float acc = 0.0f;                           // sequential k = 0..26
    #pragma unroll
    for (int v = 0; v < 9; ++v) acc = fmaf(w1r[v],      fr[v], acc);
    #pragma unroll
    for (int v = 0; v < 9; ++v) acc = fmaf(w1r[9 + v],  fc[v], acc);
    #pragma unroll
    for (int v = 0; v < 9; ++v) acc = fmaf(w1r[18 + v], fb[v], acc);
    return acc;
}

__global__ __launch_bounds__(NTHREADS)
void sudoku_solver_kernel(const float* __restrict__ x_in,
                          const float* __restrict__ W1,
                          const float* __restrict__ W2,
                          float* __restrict__ out,
                          int B)
{
    __shared__ float W2s[ND * NH];                  //  3600 B
    __shared__ float xs[NCELL * ND];                //  2916 B (current board, one-hot)
    __shared__ float xp[NCELL * ND];                //  2916 B (x_pred carry)
    __shared__ float gsum[27 * ND];                 //   972 B (row/col/box digit sums)
    alignas(16) __shared__ float hbuf[CHUNK * NH];  // 25600 B (hidden acts per chunk)
    alignas(16) __shared__ float lbuf[CHUNK * ND];  //  2304 B (logits per chunk)
    __shared__ int   elist[NCELL];                  // compacted empty-cell indices
    __shared__ float escore[NCELL];                 // per-empty-cell max softmax
    __shared__ int   epos[NCELL];                   // per-empty-cell argmax digit
    __shared__ int   Ecount;

    const int b   = blockIdx.x;
    const int tid = threadIdx.x;
    if (b >= B) return;

    // ---- layer-1 weights: register resident, thread owns hidden unit u ----
    const int u   = tid % NH;      // hidden unit (threads 0..199 active in L1)
    const int sub = tid / NH;      // which of the cell pair this thread takes
    float w1r[27];
    if (tid < 2 * NH) {
        #pragma unroll
        for (int c = 0; c < 27; ++c) w1r[c] = W1[u * 27 + c];
    }

    for (int i = tid; i < ND * NH; i += NTHREADS) W2s[i] = W2[i];
    {
        const float* xb = x_in + (size_t)b * (NCELL * ND);
        for (int i = tid; i < NCELL * ND; i += NTHREADS) {
            float v = xb[i];
            xs[i] = v;
            xp[i] = v;
        }
    }
    if (tid == 0) Ecount = 0;
    __syncthreads();

    for (int step = 0; step < NCELL; ++step) {
        // ---- phase 1: empty-cell compaction (81 tasks) + group sums (243) ----
        for (int t = tid; t < NCELL + 27 * ND; t += NTHREADS) {
            if (t < NCELL) {
                const float* r = &xs[t * ND];
                float s = r[0]+r[1]+r[2]+r[3]+r[4]+r[5]+r[6]+r[7]+r[8]; // exact {0,1}
                if (s == 0.0f) {
                    int e = atomicAdd(&Ecount, 1);
                    elist[e] = t;
                }
            } else {
                int g = (t - NCELL) / ND;   // 0..8 row, 9..17 col, 18..26 box
                int v = (t - NCELL) % ND;
                float acc = 0.0f;
                if (g < 9) {
                    int base = g * 9;
                    #pragma unroll
                    for (int j = 0; j < 9; ++j) acc += xs[(base + j) * ND + v];
                } else if (g < 18) {
                    int c = g - 9;
                    #pragma unroll
                    for (int j = 0; j < 9; ++j) acc += xs[(j * 9 + c) * ND + v];
                } else {
                    int bb = g - 18;
                    int br = (bb / 3) * 3, bc = (bb % 3) * 3;
                    #pragma unroll
                    for (int j = 0; j < 9; ++j)
                        acc += xs[((br + j / 3) * 9 + (bc + j % 3)) * ND + v];
                }
                gsum[g * ND + v] = acc;   // exact small integers
            }
        }
        __syncthreads();
        const int E = Ecount;     // every thread snapshots before any reset
        if (E == 0) break;        // all remaining reference steps are exact no-ops

        for (int c0 = 0; c0 < E; c0 += CHUNK) {
            const int C = min(CHUNK, E - c0);

            // ---- layer 1: h = relu(W1 @ f). 200 threads x 2 cells each per
            // iteration (4 cells/iter), branchless so the two 27-FMA chains
            // interleave for ILP. ----
            if (tid < 2 * NH) {
                for (int ci0 = 0; ci0 < C; ci0 += 4) {
                    int  ciA = ci0 + sub;
                    int  ciB = ci0 + 2 + sub;
                    bool pA  = ciA < C;
                    bool pB  = ciB < C;
                    int cellA = elist[c0 + (pA ? ciA : 0)];
                    int cellB = elist[c0 + (pB ? ciB : 0)];
                    float aA = l1_cell(gsum, w1r, cellA);   // two independent
                    float aB = l1_cell(gsum, w1r, cellB);   // chains, one BB
                    if (pA) hbuf[ciA * NH + u] = fmaxf(aA, 0.0f);
                    if (pB) hbuf[ciB * NH + u] = fmaxf(aB, 0.0f);
                }
            }
            __syncthreads();
            // safe point: every thread already snapshotted E (>=1 barrier ago)
            if (c0 == 0 && tid == 0) Ecount = 0;

            // ---- layer 2: logits = W2 @ h (float4 LDS reads, seq u=0..99) ----
            for (int t = tid; t < C * ND; t += NTHREADS) {
                int ci = t / ND, v = t % ND;
                const float4* w = (const float4*)&W2s[v * NH];   // 400B rows, 16B aligned
                const float4* h = (const float4*)&hbuf[ci * NH];
                float acc = 0.0f;
                #pragma unroll
                for (int q = 0; q < NH / 4; ++q) {
                    float4 wv = w[q], hv = h[q];
                    acc = fmaf(wv.x, hv.x, acc);
                    acc = fmaf(wv.y, hv.y, acc);
                    acc = fmaf(wv.z, hv.z, acc);
                    acc = fmaf(wv.w, hv.w, acc);
                }
                lbuf[t] = acc;
            }
            __syncthreads();

            // ---- softmax + per-cell score/argmax + x_pred update ----
            for (int ci = tid; ci < C; ci += NTHREADS) {
                int cell = elist[c0 + ci];
                float l[9];
                float m = -INFINITY;
                #pragma unroll
                for (int v = 0; v < 9; ++v) { l[v] = lbuf[ci * ND + v]; m = fmaxf(m, l[v]); }
                float e9[9]; float ssum = 0.0f;
                #pragma unroll
                for (int v = 0; v < 9; ++v) { e9[v] = expf(l[v] - m); ssum += e9[v]; }
                float best = -1.0f; int bp = 0;
                #pragma unroll
                for (int v = 0; v < 9; ++v) {
                    float sv = e9[v] / ssum;        // true division, like jax
                    xp[cell * ND + v] = sv;
                    if (sv > best) { best = sv; bp = v; }  // first-index tie-break
                }
                escore[c0 + ci] = best;
                epos[c0 + ci]   = bp;
            }
            __syncthreads();
        }

        // ---- pick most confident cell (max score, lowest cell idx on tie) ----
        if (tid < 64) {
            float bs = -1.0f; int bc = 0x7fffffff; int bp = 0;
            for (int e = tid; e < E; e += 64) {
                float sc = escore[e];
                int   ce = elist[e];
                if (sc > bs || (sc == bs && ce < bc)) { bs = sc; bc = ce; bp = epos[e]; }
            }
            #pragma unroll
            for (int off = 32; off > 0; off >>= 1) {
                float os = __shfl_xor(bs, off, 64);
                int   oc = __shfl_xor(bc, off, 64);
                int   op = __shfl_xor(bp, off, 64);
                if (os > bs || (os == bs && oc < bc)) { bs = os; bc = oc; bp = op; }
            }
            if (tid == 0) xs[bc * ND + bp] = 1.0f;   // fill chosen cell
        }
        __syncthreads();
    }

    // ---- output: concat(x_pred, x) ----
    const size_t outb = (size_t)b * (NCELL * ND);
    const size_t half = (size_t)B * (NCELL * ND);
    for (int i = tid; i < NCELL * ND; i += NTHREADS) {
        out[outb + i]        = xp[i];
        out[half + outb + i] = xs[i];
    }
}

extern "C" void kernel_launch(void* const* d_in, const int* in_sizes, int n_in,
                              void* d_out, int out_size, void* d_ws, size_t ws_size,
                              hipStream_t stream)
{
    const float* x  = (const float*)d_in[0];
    // d_in[1] = constraint_mask: structure is fixed (rows/cols/boxes) -> hardcoded
    const float* W1 = (const float*)d_in[2];
    const float* W2 = (const float*)d_in[3];
    float* out = (float*)d_out;
    const int B = in_sizes[0] / (NCELL * ND);

    sudoku_solver_kernel<<<dim3(B), dim3(NTHREADS), 0, stream>>>(x, W1, W2, out, B);
}

// Round 6
// 283.576 us; speedup vs baseline: 1.7591x; 1.7591x over previous
//
#include <hip/hip_runtime.h>
#include <math.h>

// Sudoku iterative solver v2: one workgroup per batch row, full 81-step scan
// in-kernel. This version collapses the per-step work algebraically:
//   (1) L1 factorized through gsum-space: PT[g][u] = dot9(W1 group g, gsum[g])
//       (27x100 table), h[cell][u] = relu(PT[row]+PT[col]+PT[box]).
//   (2) Exact incremental update: a fill changes 3 gsum entries (+1.0, exact
//       integers) -> recompute only 3 PT rows; only empty cells sharing the
//       filled cell's row/col/box ("worklist", ~20) get h/logits/softmax
//       recomputed. Unchanged cells keep bit-identical memoized values.
// Numerics: group dots in reference k-order, softmax = expf(l-max)/sum with
// per-element true division, first-index tie-breaks on both argmaxes.

#define NCELL 81
#define ND 9
#define NH 100
#define NG 27
#define NTHREADS 256

__global__ __launch_bounds__(NTHREADS)
void sudoku_solver_kernel(const float* __restrict__ x_in,
                          const float* __restrict__ W1,
                          const float* __restrict__ W2,
                          float* __restrict__ out,
                          int B)
{
    alignas(16) __shared__ float W2s[ND * NH];     //  3600 B (rows of W2, 400B each)
    alignas(16) __shared__ float hbuf[NCELL * NH]; // 32400 B (hidden acts, by CELL)
    __shared__ float xs[NCELL * ND];               //  2916 B (board, one-hot)
    __shared__ float xp[NCELL * ND];               //  2916 B (x_pred carry)
    __shared__ float gsum[NG * ND];                //   972 B (row/col/box digit sums)
    __shared__ float PT[NG * NH];                  // 10800 B (group-partial dot table)
    __shared__ float lbuf[NCELL * ND];             //  2916 B (logits, by CELL)
    __shared__ float escore[NCELL];                // memoized per-cell max prob
    __shared__ int   epos[NCELL];                  // memoized per-cell argmax digit
    __shared__ int   elist[NCELL];                 // empty-cell list
    __shared__ int   wlist[NCELL];                 // this step's recompute worklist
    __shared__ int   Ecnt, Wcnt, lastFill;

    const int b   = blockIdx.x;
    const int tid = threadIdx.x;
    if (b >= B) return;

    const int u   = tid % NH;      // hidden unit owned by this thread (tid<200)
    const int sub = tid / NH;      // 0/1 work-splitter for the 200-thread phases

    // ---- layer-1 weights register-resident (thread owns W1 row u) ----
    float w1r[NG];
    if (tid < 2 * NH) {
        #pragma unroll
        for (int k = 0; k < NG; ++k) w1r[k] = W1[u * NG + k];
    }
    for (int i = tid; i < ND * NH; i += NTHREADS) W2s[i] = W2[i];
    {
        const float* xb = x_in + (size_t)b * (NCELL * ND);
        for (int i = tid; i < NCELL * ND; i += NTHREADS) {
            float v = xb[i];
            xs[i] = v;
            xp[i] = v;
        }
    }
    if (tid == 0) Ecnt = 0;
    __syncthreads();

    // ---- prologue: full gsum (exact integers) + empty-cell compaction ----
    for (int t = tid; t < NCELL + NG * ND; t += NTHREADS) {
        if (t < NCELL) {
            const float* r = &xs[t * ND];
            float s = r[0]+r[1]+r[2]+r[3]+r[4]+r[5]+r[6]+r[7]+r[8]; // exact {0,1}
            if (s == 0.0f) { int e = atomicAdd(&Ecnt, 1); elist[e] = t; }
        } else {
            int g = (t - NCELL) / ND;   // 0..8 row, 9..17 col, 18..26 box
            int v = (t - NCELL) % ND;
            float acc = 0.0f;
            if (g < 9) {
                int base = g * 9;
                #pragma unroll
                for (int j = 0; j < 9; ++j) acc += xs[(base + j) * ND + v];
            } else if (g < 18) {
                int c = g - 9;
                #pragma unroll
                for (int j = 0; j < 9; ++j) acc += xs[(j * 9 + c) * ND + v];
            } else {
                int bb = g - 18;
                int br = (bb / 3) * 3, bc = (bb % 3) * 3;
                #pragma unroll
                for (int j = 0; j < 9; ++j)
                    acc += xs[((br + j / 3) * 9 + (bc + j % 3)) * ND + v];
            }
            gsum[g * ND + v] = acc;   // exact small integers
        }
    }
    __syncthreads();

    // ---- prologue: full PT table + worklist = all empties ----
    if (tid < 2 * NH) {
        for (int g = sub; g < NG; g += 2) {
            const float* gv = &gsum[g * ND];
            float acc = 0.0f;
            if (g < 9) {            // compile-time w1r indices in each branch
                #pragma unroll
                for (int v = 0; v < ND; ++v) acc = fmaf(w1r[v],      gv[v], acc);
            } else if (g < 18) {
                #pragma unroll
                for (int v = 0; v < ND; ++v) acc = fmaf(w1r[9 + v],  gv[v], acc);
            } else {
                #pragma unroll
                for (int v = 0; v < ND; ++v) acc = fmaf(w1r[18 + v], gv[v], acc);
            }
            PT[g * NH + u] = acc;
        }
    }
    for (int i = tid; i < Ecnt; i += NTHREADS) wlist[i] = elist[i];
    if (tid == 0) { Wcnt = Ecnt; lastFill = -1; }
    __syncthreads();

    // =========================== scan loop ===========================
    while (true) {
        const int E = Ecnt;
        const int W = Wcnt;
        if (E == 0) break;      // all remaining reference steps are exact no-ops

        // ---- A: recompute the 3 PT rows whose gsum changed (bit-exact) ----
        const int lf = lastFill;
        if (lf >= 0 && tid < 2 * NH) {
            int fr = lf / 9, fc = lf % 9;
            if (sub == 0) {
                const float* gv = &gsum[fr * ND];            // row group, base 0
                float acc = 0.0f;
                #pragma unroll
                for (int v = 0; v < ND; ++v) acc = fmaf(w1r[v], gv[v], acc);
                PT[fr * NH + u] = acc;
                int gb = 18 + (fr / 3) * 3 + fc / 3;         // box group, base 18
                const float* gv2 = &gsum[gb * ND];
                float acc2 = 0.0f;
                #pragma unroll
                for (int v = 0; v < ND; ++v) acc2 = fmaf(w1r[18 + v], gv2[v], acc2);
                PT[gb * NH + u] = acc2;
            } else {
                int gc = 9 + fc;                             // col group, base 9
                const float* gv = &gsum[gc * ND];
                float acc = 0.0f;
                #pragma unroll
                for (int v = 0; v < ND; ++v) acc = fmaf(w1r[9 + v], gv[v], acc);
                PT[gc * NH + u] = acc;
            }
        }
        __syncthreads();

        // ---- B: h[cell][u] = relu((PT[row]+PT[col])+PT[box]) for worklist ----
        if (tid < 2 * NH) {
            for (int wi = sub; wi < W; wi += 2) {
                int cell = wlist[wi];
                int r = cell / 9, c = cell % 9;
                int bg = 18 + (r / 3) * 3 + c / 3;
                float h = (PT[r * NH + u] + PT[(9 + c) * NH + u]) + PT[bg * NH + u];
                hbuf[cell * NH + u] = fmaxf(h, 0.0f);
            }
        }
        __syncthreads();

        // ---- C: logits for worklist cells (float4 LDS, 2 accumulators) ----
        for (int t = tid; t < W * ND; t += NTHREADS) {
            int wi = t / ND, v = t - wi * ND;
            int cell = wlist[wi];
            const float4* w4 = (const float4*)&W2s[v * NH];
            const float4* h4 = (const float4*)&hbuf[cell * NH];
            float a0 = 0.0f, a1 = 0.0f;
            #pragma unroll
            for (int q = 0; q < NH / 4; ++q) {
                float4 wv = w4[q], hv = h4[q];
                a0 = fmaf(wv.x, hv.x, a0);
                a0 = fmaf(wv.y, hv.y, a0);
                a1 = fmaf(wv.z, hv.z, a1);
                a1 = fmaf(wv.w, hv.w, a1);
            }
            lbuf[cell * ND + v] = a0 + a1;
        }
        __syncthreads();

        // ---- D: softmax + score/argmax + x_pred for worklist cells ----
        for (int wi = tid; wi < W; wi += NTHREADS) {
            int cell = wlist[wi];
            float l[9];
            float m = -INFINITY;
            #pragma unroll
            for (int v = 0; v < ND; ++v) { l[v] = lbuf[cell * ND + v]; m = fmaxf(m, l[v]); }
            float e9[9]; float ss = 0.0f;
            #pragma unroll
            for (int v = 0; v < ND; ++v) { e9[v] = expf(l[v] - m); ss += e9[v]; }
            float best = -1.0f; int bp = 0;
            #pragma unroll
            for (int v = 0; v < ND; ++v) {
                float sv = e9[v] / ss;          // true division, like jax
                xp[cell * ND + v] = sv;
                if (sv > best) { best = sv; bp = v; }  // first-index tie-break
            }
            escore[cell] = best;
            epos[cell]   = bp;
        }
        __syncthreads();

        // ---- E: argmax over all empties + fill + exact incremental update ----
        if (tid < 64) {
            float bs = -1.0f; int bc = 0x7fffffff, bp = 0, be = 0;
            for (int e = tid; e < E; e += 64) {
                int ce = elist[e];
                float sc = escore[ce];
                if (sc > bs || (sc == bs && ce < bc)) { bs = sc; bc = ce; bp = epos[ce]; be = e; }
            }
            #pragma unroll
            for (int off = 32; off > 0; off >>= 1) {
                float os = __shfl_xor(bs, off, 64);
                int   oc = __shfl_xor(bc, off, 64);
                int   op = __shfl_xor(bp, off, 64);
                int   oe = __shfl_xor(be, off, 64);
                if (os > bs || (os == bs && oc < bc)) { bs = os; bc = oc; bp = op; be = oe; }
            }
            // all 64 lanes now agree on (bc, bp, be)
            int fr = bc / 9, fc = bc % 9, fb = (fr / 3) * 3 + fc / 3;
            if (tid == 0) Wcnt = 0;           // lockstep: executes before loop below
            // rebuild worklist from pre-removal elist (reads precede the write below)
            for (int e = tid; e < E; e += 64) {
                int ce = elist[e];
                if (ce != bc) {
                    int r = ce / 9, c = ce % 9;
                    if (r == fr || c == fc || ((r / 3) * 3 + c / 3) == fb) {
                        int wi2 = atomicAdd(&Wcnt, 1);
                        wlist[wi2] = ce;
                    }
                }
            }
            if (tid == 0) {
                xs[bc * ND + bp] = 1.0f;                  // fill chosen cell
                gsum[fr * ND + bp]        += 1.0f;        // exact integer +1
                gsum[(9 + fc) * ND + bp]  += 1.0f;
                gsum[(18 + fb) * ND + bp] += 1.0f;
                elist[be] = elist[E - 1];                 // remove filled cell
                Ecnt = E - 1;
                lastFill = bc;
            }
        }
        __syncthreads();
    }

    // ---- output: concat(x_pred, x) ----
    const size_t outb = (size_t)b * (NCELL * ND);
    const size_t half = (size_t)B * (NCELL * ND);
    for (int i = tid; i < NCELL * ND; i += NTHREADS) {
        out[outb + i]        = xp[i];
        out[half + outb + i] = xs[i];
    }
}

extern "C" void kernel_launch(void* const* d_in, const int* in_sizes, int n_in,
                              void* d_out, int out_size, void* d_ws, size_t ws_size,
                              hipStream_t stream)
{
    const float* x  = (const float*)d_in[0];
    // d_in[1] = constraint_mask: fixed row/col/box structure -> hardcoded
    const float* W1 = (const float*)d_in[2];
    const float* W2 = (const float*)d_in[3];
    float* out = (float*)d_out;
    const int B = in_sizes[0] / (NCELL * ND);

    sudoku_solver_kernel<<<dim3(B), dim3(NTHREADS), 0, stream>>>(x, W1, W2, out, B);
}

// Round 8
// 249.460 us; speedup vs baseline: 1.9996x; 1.1368x over previous
//
#include <hip/hip_runtime.h>
#include <math.h>

// Sudoku solver v3: 2 barriers/step (was 5).
//  P2 (fused B+C+D): lane owns (cell-slot, digit); logit computed straight from
//    PT with register-resident W2 row; softmax via 9-lane shfl exchange. No
//    hbuf/lbuf/W2s LDS.
//  P1 (fused E+A): argmax reduce done redundantly by ALL waves (same input ->
//    same result, no broadcast barrier); u-threads recompute the 3 changed PT
//    rows from stale gsum + exact in-register +1.0 correction; wave0 rebuilds
//    the worklist; W counted redundantly via ballot.
//  Deferred writes: gsum/xs/elist compaction applied by always-idle tid63 at
//    the START of the next P2 (barrier-separated from all readers); final
//    pending fill applied in the epilogue.
// Numerics: bit-identical composition to the PASSING v2 kernel: PT dot9 in
// k-order; h=(PTr+PTc)+PTb relu'd; logits with a0(x,y)/a1(z,w) accumulator
// split then a0+a1; softmax expf(l-max)/sum ascending; first-index tie-breaks
// (score ties by lowest cell id).

#define NCELL 81
#define ND 9
#define NH 100
#define NG 27
#define NTHREADS 256

__global__ __launch_bounds__(NTHREADS, 2)
void sudoku_solver_kernel(const float* __restrict__ x_in,
                          const float* __restrict__ W1,
                          const float* __restrict__ W2,
                          float* __restrict__ out,
                          int B)
{
    __shared__ float xs[NCELL * ND];               // board (one-hot)
    __shared__ float xp[NCELL * ND];               // x_pred carry
    __shared__ float gsum[NG * ND];                // row/col/box digit sums
    alignas(16) __shared__ float PT[NG * NH];      // group-partial dot table
    __shared__ float escore[NCELL];                // memoized per-cell max prob
    __shared__ int   epos[NCELL];                  // memoized per-cell argmax digit
    __shared__ int   elist[NCELL];                 // empty-cell list
    __shared__ int   wlist[NCELL];                 // recompute worklist (cell ids)
    __shared__ int   EcntS, Wcnt;

    const int b   = blockIdx.x;
    const int tid = threadIdx.x;
    if (b >= B) return;

    const int lane = tid & 63;
    const int wv   = tid >> 6;
    const int sgrp = lane / 9;            // cell-slot within wave, 0..7 (7 = idle)
    const int vd   = lane - 9 * sgrp;     // digit owned by this lane, 0..8
    const int u    = tid % NH;            // hidden unit owned (tid<200)
    const int sub  = tid / NH;

    // ---- register-resident weights ----
    float w1r[NG];
    if (tid < 2 * NH) {
        #pragma unroll
        for (int k = 0; k < NG; ++k) w1r[k] = W1[u * NG + k];
    }
    float4 w2r[25];                        // W2 row for this lane's digit
    {
        const float4* w2row = (const float4*)&W2[vd * NH];   // 400B rows, aligned
        #pragma unroll
        for (int q = 0; q < 25; ++q) w2r[q] = w2row[q];
    }

    // ---- load board ----
    {
        const float* xb = x_in + (size_t)b * (NCELL * ND);
        for (int i = tid; i < NCELL * ND; i += NTHREADS) {
            float v = xb[i];
            xs[i] = v;
            xp[i] = v;
        }
    }
    if (tid == 0) EcntS = 0;
    __syncthreads();

    // ---- prologue: gsum (exact ints) + empty compaction ----
    for (int t = tid; t < NCELL + NG * ND; t += NTHREADS) {
        if (t < NCELL) {
            const float* r = &xs[t * ND];
            float s = r[0]+r[1]+r[2]+r[3]+r[4]+r[5]+r[6]+r[7]+r[8];
            if (s == 0.0f) { int e = atomicAdd(&EcntS, 1); elist[e] = t; }
        } else {
            int g = (t - NCELL) / ND;
            int v = (t - NCELL) % ND;
            float acc = 0.0f;
            if (g < 9) {
                int base = g * 9;
                #pragma unroll
                for (int j = 0; j < 9; ++j) acc += xs[(base + j) * ND + v];
            } else if (g < 18) {
                int c = g - 9;
                #pragma unroll
                for (int j = 0; j < 9; ++j) acc += xs[(j * 9 + c) * ND + v];
            } else {
                int bb = g - 18;
                int br = (bb / 3) * 3, bc2 = (bb % 3) * 3;
                #pragma unroll
                for (int j = 0; j < 9; ++j)
                    acc += xs[((br + j / 3) * 9 + (bc2 + j % 3)) * ND + v];
            }
            gsum[g * ND + v] = acc;
        }
    }
    __syncthreads();

    // ---- prologue: full PT + worklist = all empties ----
    int E_reg = EcntS;
    if (tid < 2 * NH) {
        for (int g = sub; g < NG; g += 2) {
            const float* gv = &gsum[g * ND];
            float acc = 0.0f;
            if (g < 9) {
                #pragma unroll
                for (int v = 0; v < ND; ++v) acc = fmaf(w1r[v],      gv[v], acc);
            } else if (g < 18) {
                #pragma unroll
                for (int v = 0; v < ND; ++v) acc = fmaf(w1r[9 + v],  gv[v], acc);
            } else {
                #pragma unroll
                for (int v = 0; v < ND; ++v) acc = fmaf(w1r[18 + v], gv[v], acc);
            }
            PT[g * NH + u] = acc;
        }
    }
    for (int i = tid; i < E_reg; i += NTHREADS) wlist[i] = elist[i];
    __syncthreads();

    int W_reg = E_reg;
    int pend_cell = -1, pend_digit = 0, pend_be = 0;

    // =========================== scan loop: 2 barriers/step ===========================
    while (E_reg > 0) {
        // ---- P2: apply pending state (tid63) + fused h/logit/softmax ----
        if (tid == 63) {
            Wcnt = 0;
            if (pend_cell >= 0) {
                int fr = pend_cell / 9, fc = pend_cell % 9;
                int fb = (fr / 3) * 3 + fc / 3;
                xs[pend_cell * ND + pend_digit] = 1.0f;
                gsum[fr * ND + pend_digit]        += 1.0f;   // exact integer +1
                gsum[(9 + fc) * ND + pend_digit]  += 1.0f;
                gsum[(18 + fb) * ND + pend_digit] += 1.0f;
                elist[pend_be] = elist[E_reg];               // compact (old size = E_reg+1)
            }
        }
        const int npass = (W_reg + 27) / 28;
        for (int pass = 0; pass < npass; ++pass) {
            int ci = pass * 28 + wv * 7 + sgrp;
            if (sgrp < 7 && ci < W_reg) {
                int cell = wlist[ci];
                int r = cell / 9, c = cell - 9 * r;
                int bg = 18 + (r / 3) * 3 + c / 3;
                const float4* p_r = (const float4*)&PT[r * NH];
                const float4* p_c = (const float4*)&PT[(9 + c) * NH];
                const float4* p_b = (const float4*)&PT[bg * NH];
                float a0 = 0.0f, a1 = 0.0f;
                #pragma unroll
                for (int q = 0; q < 25; ++q) {
                    float4 hr = p_r[q], hc = p_c[q], hb = p_b[q];
                    float hx = fmaxf((hr.x + hc.x) + hb.x, 0.0f);
                    float hy = fmaxf((hr.y + hc.y) + hb.y, 0.0f);
                    float hz = fmaxf((hr.z + hc.z) + hb.z, 0.0f);
                    float hw = fmaxf((hr.w + hc.w) + hb.w, 0.0f);
                    float4 w = w2r[q];
                    a0 = fmaf(w.x, hx, a0);
                    a0 = fmaf(w.y, hy, a0);
                    a1 = fmaf(w.z, hz, a1);
                    a1 = fmaf(w.w, hw, a1);
                }
                float l_own = a0 + a1;
                // softmax across the 9 lanes of this cell group (intra-wave)
                float l[9];
                #pragma unroll
                for (int j = 0; j < 9; ++j) l[j] = __shfl(l_own, 9 * sgrp + j, 64);
                float m = -INFINITY;
                #pragma unroll
                for (int j = 0; j < 9; ++j) m = fmaxf(m, l[j]);
                float e9[9]; float ss = 0.0f;
                #pragma unroll
                for (int j = 0; j < 9; ++j) { e9[j] = expf(l[j] - m); ss += e9[j]; }
                float best = -1.0f; int bp = 0; float svown = 0.0f;
                #pragma unroll
                for (int j = 0; j < 9; ++j) {
                    float sv = e9[j] / ss;            // true division, like jax
                    if (j == vd) svown = sv;
                    if (sv > best) { best = sv; bp = j; }   // first-index tie-break
                }
                xp[cell * ND + vd] = svown;
                if (vd == 0) { escore[cell] = best; epos[cell] = bp; }
            }
        }
        __syncthreads();   // escore/epos/xp + pending-state writes visible

        // ---- P1: redundant argmax reduce (all waves) ----
        float bs = -1.0f; int bc = 0x7fffffff, bp = 0, be = 0;
        for (int e = lane; e < E_reg; e += 64) {
            int ce = elist[e];
            float sc = escore[ce];
            if (sc > bs || (sc == bs && ce < bc)) { bs = sc; bc = ce; bp = epos[ce]; be = e; }
        }
        #pragma unroll
        for (int off = 32; off > 0; off >>= 1) {
            float os = __shfl_xor(bs, off, 64);
            int   oc = __shfl_xor(bc, off, 64);
            int   op = __shfl_xor(bp, off, 64);
            int   oe = __shfl_xor(be, off, 64);
            if (os > bs || (os == bs && oc < bc)) { bs = os; bc = oc; bp = op; be = oe; }
        }
        // every thread now knows the fill (bc, bp, be)
        const int fr = bc / 9, fc = bc % 9, fb = (fr / 3) * 3 + fc / 3;

        // worklist: count redundantly (ballot), wave0 builds the list
        int Wn = 0;
        for (int base = 0; base < E_reg; base += 64) {
            int e = base + lane;
            bool pr = false;
            int ce = 0;
            if (e < E_reg && e != be) {
                ce = elist[e];
                int r = ce / 9, c = ce - 9 * r;
                pr = (r == fr) || (c == fc) || (((r / 3) * 3 + c / 3) == fb);
            }
            unsigned long long mask = __ballot(pr);
            Wn += (int)__popcll(mask);
            if (wv == 0 && pr) { int w = atomicAdd(&Wcnt, 1); wlist[w] = ce; }
        }

        // PT recompute for the 3 changed rows: stale gsum + exact +1 correction
        if (tid < 2 * NH) {
            if (sub == 0) {
                const float* gv = &gsum[fr * ND];
                float acc = 0.0f;
                #pragma unroll
                for (int v = 0; v < ND; ++v) {
                    float g = gv[v] + ((v == bp) ? 1.0f : 0.0f);
                    acc = fmaf(w1r[v], g, acc);
                }
                PT[fr * NH + u] = acc;
                const float* gv2 = &gsum[(18 + fb) * ND];
                float acc2 = 0.0f;
                #pragma unroll
                for (int v = 0; v < ND; ++v) {
                    float g = gv2[v] + ((v == bp) ? 1.0f : 0.0f);
                    acc2 = fmaf(w1r[18 + v], g, acc2);
                }
                PT[(18 + fb) * NH + u] = acc2;
            } else {
                const float* gv = &gsum[(9 + fc) * ND];
                float acc = 0.0f;
                #pragma unroll
                for (int v = 0; v < ND; ++v) {
                    float g = gv[v] + ((v == bp) ? 1.0f : 0.0f);
                    acc = fmaf(w1r[9 + v], g, acc);
                }
                PT[(9 + fc) * NH + u] = acc;
            }
        }

        E_reg -= 1;
        pend_cell = bc; pend_digit = bp; pend_be = be;
        W_reg = Wn;
        __syncthreads();   // PT + wlist visible for next P2
    }

    // ---- epilogue: apply final pending fill, then write out ----
    if (tid == 63 && pend_cell >= 0) xs[pend_cell * ND + pend_digit] = 1.0f;
    __syncthreads();

    const size_t outb = (size_t)b * (NCELL * ND);
    const size_t half = (size_t)B * (NCELL * ND);
    for (int i = tid; i < NCELL * ND; i += NTHREADS) {
        out[outb + i]        = xp[i];
        out[half + outb + i] = xs[i];
    }
}

extern "C" void kernel_launch(void* const* d_in, const int* in_sizes, int n_in,
                              void* d_out, int out_size, void* d_ws, size_t ws_size,
                              hipStream_t stream)
{
    const float* x  = (const float*)d_in[0];
    // d_in[1] = constraint_mask: fixed row/col/box structure -> hardcoded
    const float* W1 = (const float*)d_in[2];
    const float* W2 = (const float*)d_in[3];
    float* out = (float*)d_out;
    const int B = in_sizes[0] / (NCELL * ND);

    sudoku_solver_kernel<<<dim3(B), dim3(NTHREADS), 0, stream>>>(x, W1, W2, out, B);
}

// Round 10
// 206.596 us; speedup vs baseline: 2.4145x; 1.2075x over previous
//
#include <hip/hip_runtime.h>
#include <math.h>

// Sudoku solver v4: attack the LDS issue pipe (v3 post-mortem: ~900 LDS
// insts/step/CU ~= the whole step time).
//  P2a: block-wide h staging -- h[cell][u]=relu((PTr+PTc)+PTb) produced once
//       per worklist cell into hs[][] (distinct reads, ~10 LDS insts/wave)
//       instead of every digit-lane broadcast-reading 3 full PT rows (75).
//  P2b: consumption reads only hs[ci] (25 insts) + register-resident W2 row.
//  P1:  argmax packed into one u64 (score|cell|e) -> 12 bperm not 24;
//       PT recompute with float4 gsum reads (rows padded to 12 floats).
// 3 barriers/step (was 2; producer->consumer needs one).
// Numerics bit-identical to PASSING v3: PT dot9 k-ascending; h=(r+c)+b relu;
// a0(x,y)/a1(z,w) dot split then a0+a1; softmax expf(l-max)/sum ascending,
// true division; tie-breaks: first-index digits, lowest cell id on score tie.

#define NCELL 81
#define ND 9
#define NH 100
#define NG 27
#define GP 12          // padded gsum row stride (floats) for float4 reads
#define NTHREADS 256

template<int OFF>
__device__ __forceinline__ float pt_dot(const float* __restrict__ gr,
                                        const float (&w1r)[NG], int bp)
{
    float g[9];
    float4 ga = *(const float4*)gr;         // 48B row stride -> 16B aligned
    float4 gb = *(const float4*)(gr + 4);
    g[0]=ga.x; g[1]=ga.y; g[2]=ga.z; g[3]=ga.w;
    g[4]=gb.x; g[5]=gb.y; g[6]=gb.z; g[7]=gb.w;
    g[8]=gr[8];
    float acc = 0.0f;
    #pragma unroll
    for (int v = 0; v < 9; ++v)             // k-ascending, compile-time idx
        acc = fmaf(w1r[OFF + v], g[v] + ((v == bp) ? 1.0f : 0.0f), acc);
    return acc;
}

__global__ __launch_bounds__(NTHREADS, 2)
void sudoku_solver_kernel(const float* __restrict__ x_in,
                          const float* __restrict__ W1,
                          const float* __restrict__ W2,
                          float* __restrict__ out,
                          int B)
{
    __shared__ float xs[NCELL * ND];                 // board (one-hot)
    __shared__ float xp[NCELL * ND];                 // x_pred carry
    alignas(16) __shared__ float gsum[NG * GP];      // padded digit sums
    alignas(16) __shared__ float PT[NG * NH];        // group-partial dot table
    alignas(16) __shared__ float hs[NCELL * NH];     // staged h per worklist cell
    __shared__ float escore[NCELL];
    __shared__ int   epos[NCELL];
    __shared__ int   elist[NCELL];
    __shared__ int   wlist[NCELL];
    __shared__ int   EcntS, Wcnt;

    const int b   = blockIdx.x;
    const int tid = threadIdx.x;
    if (b >= B) return;

    const int lane = tid & 63;
    const int wv   = tid >> 6;
    const int sgrp = lane / 9;            // cell-slot in wave, 0..7 (7 idle)
    const int vd   = lane - 9 * sgrp;     // digit owned, 0..8
    const int u    = tid % NH;            // hidden unit owned (tid<200)
    const int sub  = tid / NH;

    // ---- register-resident weights ----
    float w1r[NG];
    if (tid < 2 * NH) {
        #pragma unroll
        for (int k = 0; k < NG; ++k) w1r[k] = W1[u * NG + k];
    }
    float4 w2r[25];
    {
        const float4* w2row = (const float4*)&W2[vd * NH];
        #pragma unroll
        for (int q = 0; q < 25; ++q) w2r[q] = w2row[q];
    }

    // ---- load board ----
    {
        const float* xb = x_in + (size_t)b * (NCELL * ND);
        for (int i = tid; i < NCELL * ND; i += NTHREADS) {
            float v = xb[i];
            xs[i] = v;
            xp[i] = v;
        }
    }
    if (tid == 0) EcntS = 0;
    __syncthreads();

    // ---- prologue: gsum (exact ints, padded rows) + empty compaction ----
    for (int t = tid; t < NCELL + NG * ND; t += NTHREADS) {
        if (t < NCELL) {
            const float* r = &xs[t * ND];
            float s = r[0]+r[1]+r[2]+r[3]+r[4]+r[5]+r[6]+r[7]+r[8];
            if (s == 0.0f) { int e = atomicAdd(&EcntS, 1); elist[e] = t; }
        } else {
            int g = (t - NCELL) / ND;
            int v = (t - NCELL) % ND;
            float acc = 0.0f;
            if (g < 9) {
                int base = g * 9;
                #pragma unroll
                for (int j = 0; j < 9; ++j) acc += xs[(base + j) * ND + v];
            } else if (g < 18) {
                int c = g - 9;
                #pragma unroll
                for (int j = 0; j < 9; ++j) acc += xs[(j * 9 + c) * ND + v];
            } else {
                int bb = g - 18;
                int br = (bb / 3) * 3, bc2 = (bb % 3) * 3;
                #pragma unroll
                for (int j = 0; j < 9; ++j)
                    acc += xs[((br + j / 3) * 9 + (bc2 + j % 3)) * ND + v];
            }
            gsum[g * GP + v] = acc;
        }
    }
    __syncthreads();

    // ---- prologue: full PT + worklist = all empties ----
    int E_reg = EcntS;
    if (tid < 2 * NH) {
        for (int g = sub; g < NG; g += 2) {
            float acc;
            if (g < 9)       acc = pt_dot<0>(&gsum[g * GP], w1r, -1);
            else if (g < 18) acc = pt_dot<9>(&gsum[g * GP], w1r, -1);
            else             acc = pt_dot<18>(&gsum[g * GP], w1r, -1);
            PT[g * NH + u] = acc;
        }
    }
    for (int i = tid; i < E_reg; i += NTHREADS) wlist[i] = elist[i];
    __syncthreads();

    int W_reg = E_reg;
    int pend_cell = -1, pend_digit = 0, pend_be = 0;

    // ================= scan loop: 3 barriers/step =================
    while (E_reg > 0) {
        // ---- P2a: apply pending state + block-wide h staging ----
        if (tid == NTHREADS - 1) {
            Wcnt = 0;
            if (pend_cell >= 0) {
                int fr = pend_cell / 9, fc = pend_cell % 9;
                int fb = (fr / 3) * 3 + fc / 3;
                xs[pend_cell * ND + pend_digit] = 1.0f;
                gsum[fr * GP + pend_digit]        += 1.0f;   // exact int +1
                gsum[(9 + fc) * GP + pend_digit]  += 1.0f;
                gsum[(18 + fb) * GP + pend_digit] += 1.0f;
                elist[pend_be] = elist[E_reg];               // compact
            }
        }
        for (int ch = tid; ch < W_reg * 25; ch += NTHREADS) {
            int wi = ch / 25, qc = ch - 25 * wi;
            int cell = wlist[wi];
            int r = cell / 9, c = cell - 9 * r;
            int bg = 18 + (r / 3) * 3 + c / 3;
            float4 hr = ((const float4*)&PT[r * NH])[qc];
            float4 hc = ((const float4*)&PT[(9 + c) * NH])[qc];
            float4 hb = ((const float4*)&PT[bg * NH])[qc];
            float4 h;
            h.x = fmaxf((hr.x + hc.x) + hb.x, 0.0f);
            h.y = fmaxf((hr.y + hc.y) + hb.y, 0.0f);
            h.z = fmaxf((hr.z + hc.z) + hb.z, 0.0f);
            h.w = fmaxf((hr.w + hc.w) + hb.w, 0.0f);
            ((float4*)&hs[wi * NH])[qc] = h;
        }
        __syncthreads();

        // ---- P2b: logits + softmax + memoized score/argmax ----
        const int npass = (W_reg + 27) / 28;
        for (int pass = 0; pass < npass; ++pass) {
            int ci = pass * 28 + wv * 7 + sgrp;
            if (sgrp < 7 && ci < W_reg) {
                int cell = wlist[ci];
                const float4* h4 = (const float4*)&hs[ci * NH];
                float a0 = 0.0f, a1 = 0.0f;
                #pragma unroll
                for (int q = 0; q < 25; ++q) {
                    float4 hv = h4[q], w = w2r[q];
                    a0 = fmaf(w.x, hv.x, a0);
                    a0 = fmaf(w.y, hv.y, a0);
                    a1 = fmaf(w.z, hv.z, a1);
                    a1 = fmaf(w.w, hv.w, a1);
                }
                float l_own = a0 + a1;
                float l[9];
                #pragma unroll
                for (int j = 0; j < 9; ++j) l[j] = __shfl(l_own, 9 * sgrp + j, 64);
                float m = -INFINITY;
                #pragma unroll
                for (int j = 0; j < 9; ++j) m = fmaxf(m, l[j]);
                float e9[9]; float ss = 0.0f;
                #pragma unroll
                for (int j = 0; j < 9; ++j) { e9[j] = expf(l[j] - m); ss += e9[j]; }
                float best = -1.0f; int bp = 0; float svown = 0.0f;
                #pragma unroll
                for (int j = 0; j < 9; ++j) {
                    float sv = e9[j] / ss;          // true division, like jax
                    if (j == vd) svown = sv;
                    if (sv > best) { best = sv; bp = j; }   // first-index tie
                }
                xp[cell * ND + vd] = svown;
                if (vd == 0) { escore[cell] = best; epos[cell] = bp; }
            }
        }
        __syncthreads();

        // ---- P1: packed-u64 argmax + worklist + PT recompute ----
        unsigned long long key = 0ULL;
        for (int e = lane; e < E_reg; e += 64) {
            int ce = elist[e];
            float sc = escore[ce];                  // > 0 always
            unsigned int lo = ((unsigned)(NCELL - ce) << 7) | (unsigned)e;
            unsigned long long k =
                ((unsigned long long)__float_as_uint(sc) << 32) | lo;
            if (k > key) key = k;                   // score desc, cell asc
        }
        #pragma unroll
        for (int off = 32; off > 0; off >>= 1) {
            unsigned long long ok = __shfl_xor(key, off, 64);
            if (ok > key) key = ok;
        }
        const unsigned int lo = (unsigned int)key;
        const int bc = NCELL - (int)(lo >> 7);
        const int be = (int)(lo & 127);
        const int bp = epos[bc];                    // broadcast read
        const int fr = bc / 9, fc = bc % 9, fb = (fr / 3) * 3 + fc / 3;

        // worklist: count redundantly (ballot), wave0 builds the list
        int Wn = 0;
        for (int base = 0; base < E_reg; base += 64) {
            int e = base + lane;
            bool pr = false;
            int ce = 0;
            if (e < E_reg && e != be) {
                ce = elist[e];
                int r = ce / 9, c = ce - 9 * r;
                pr = (r == fr) || (c == fc) || (((r / 3) * 3 + c / 3) == fb);
            }
            unsigned long long mask = __ballot(pr);
            Wn += (int)__popcll(mask);
            if (wv == 0 && pr) { int w = atomicAdd(&Wcnt, 1); wlist[w] = ce; }
        }

        // PT recompute: stale gsum + exact in-register +1 at digit bp
        if (tid < 2 * NH) {
            if (sub == 0) {
                PT[fr * NH + u]        = pt_dot<0>(&gsum[fr * GP], w1r, bp);
                PT[(18 + fb) * NH + u] = pt_dot<18>(&gsum[(18 + fb) * GP], w1r, bp);
            } else {
                PT[(9 + fc) * NH + u]  = pt_dot<9>(&gsum[(9 + fc) * GP], w1r, bp);
            }
        }

        E_reg -= 1;
        pend_cell = bc; pend_digit = bp; pend_be = be;
        W_reg = Wn;
        __syncthreads();   // PT + wlist + escore consistent for next P2a
    }

    // ---- epilogue: apply final pending fill, then write out ----
    if (tid == NTHREADS - 1 && pend_cell >= 0)
        xs[pend_cell * ND + pend_digit] = 1.0f;
    __syncthreads();

    const size_t outb = (size_t)b * (NCELL * ND);
    const size_t half = (size_t)B * (NCELL * ND);
    for (int i = tid; i < NCELL * ND; i += NTHREADS) {
        out[outb + i]        = xp[i];
        out[half + outb + i] = xs[i];
    }
}

extern "C" void kernel_launch(void* const* d_in, const int* in_sizes, int n_in,
                              void* d_out, int out_size, void* d_ws, size_t ws_size,
                              hipStream_t stream)
{
    const float* x  = (const float*)d_in[0];
    // d_in[1] = constraint_mask: fixed row/col/box structure -> hardcoded
    const float* W1 = (const float*)d_in[2];
    const float* W2 = (const float*)d_in[3];
    float* out = (float*)d_out;
    const int B = in_sizes[0] / (NCELL * ND);

    sudoku_solver_kernel<<<dim3(B), dim3(NTHREADS), 0, stream>>>(x, W1, W2, out, B);
}